// Round 7
// baseline (465.409 us; speedup 1.0000x reference)
//
#include <hip/hip_runtime.h>
#include <stdint.h>

// Problem dims (fixed by the reference)
#define TT 256
#define SS 256
#define FF 1024
#define AA 256

typedef __attribute__((ext_vector_type(8))) short short8;
typedef __attribute__((ext_vector_type(4))) float floatx4;

// fp32 -> bf16 round-to-nearest-even
__device__ __forceinline__ unsigned short f2bf(float f) {
  unsigned int u = __float_as_uint(f);
  u += 0x7FFFu + ((u >> 16) & 1u);
  return (unsigned short)(u >> 16);
}

// async global->LDS, 16 B per lane; LDS dest = wave-uniform base + lane*16
__device__ __forceinline__ void gl_lds16(const unsigned short* g, unsigned short* l) {
  __builtin_amdgcn_global_load_lds(
      (__attribute__((address_space(1))) void*)(g),
      (__attribute__((address_space(3))) void*)(l), 16, 0, 0);
}

// ---------------------------------------------------------------------------
// Weight transpose + fp32->bf16:  WT[n][k] = bf16(W[k][n]).  W: K x N fp32.
// ---------------------------------------------------------------------------
__global__ void k_transpose_cvt(const float* __restrict__ W,
                                unsigned short* __restrict__ WT,
                                int K, int N) {
  __shared__ float tile[32][33];
  const int bk = blockIdx.x * 32, bn = blockIdx.y * 32;
  const int tx = threadIdx.x, ty = threadIdx.y;
  for (int i = ty; i < 32; i += 8)
    tile[i][tx] = W[(size_t)(bk + i) * N + bn + tx];
  __syncthreads();
  for (int i = ty; i < 32; i += 8)
    WT[(size_t)(bn + i) * K + bk + tx] = f2bf(tile[tx][i]);
}

// ---------------------------------------------------------------------------
// Shared pieces for the 256x256 / BK=64 / 8-wave 8-phase GEMM structure.
// LDS 128 KiB: A[2buf][2half][128][64] | B[...]; half-tiles staged via
// global_load_lds (bf16 inputs) with counted vmcnt.
// T2 swizzle: LDS granule gl of row r holds global granule gl ^ (r&7)
// (pre-swizzled source for gl_lds; explicit XOR for reg-staged writes);
// reads use col ^ ((row&7)<<3)  -> conflict-free (measured 0).
// ---------------------------------------------------------------------------
__device__ __forceinline__ void stage_half(const unsigned short* G, int ld,
                                           unsigned short* L, int tid) {
  // G points at (row0, k0) of a 128x64 half-tile, leading dim = ld elems.
  const int wave = tid >> 6, lane = tid & 63;
#pragma unroll
  for (int c = 0; c < 2; ++c) {
    const int chunk = c * 8 + wave;            // 16 chunks of 8 rows
    const int r = chunk * 8 + (lane >> 3);     // local row 0..127
    const int k8 = (lane & 7) ^ (lane >> 3);   // swizzled source 16B-granule
    gl_lds16(G + (size_t)r * ld + k8 * 8, L + chunk * 512);
  }
}

__device__ __forceinline__ short8 ldsfrag(const unsigned short* h, int row,
                                          int col) {
  return *(const short8*)&h[row * 64 + (col ^ ((row & 7) << 3))];
}

// ---- fp32 A-side reg-staging (fused convert; T14 issue-early/write-late) ----
struct A4 { floatx4 v0, v1, v2, v3; };

// Thread (ar = tid>>2, ag = (tid&3)*2) loads 16 consecutive floats of row ar:
// granules ag, ag+1 (8 floats each) of a 128x64 fp32 half-tile.
__device__ __forceinline__ A4 a_load(const float* G, int ar, int ag) {
  const float* p = G + (size_t)ar * FF + ag * 8;
  A4 a;
  a.v0 = *(const floatx4*)(p);
  a.v1 = *(const floatx4*)(p + 4);
  a.v2 = *(const floatx4*)(p + 8);
  a.v3 = *(const floatx4*)(p + 12);
  return a;
}

// Convert + write to the T2-swizzled LDS position: granule g -> g ^ (ar&7).
__device__ __forceinline__ void a_write(unsigned short* L, int ar, int ag,
                                        const A4& a) {
  short8 h0, h1;
  h0[0] = (short)f2bf(a.v0.x); h0[1] = (short)f2bf(a.v0.y);
  h0[2] = (short)f2bf(a.v0.z); h0[3] = (short)f2bf(a.v0.w);
  h0[4] = (short)f2bf(a.v1.x); h0[5] = (short)f2bf(a.v1.y);
  h0[6] = (short)f2bf(a.v1.z); h0[7] = (short)f2bf(a.v1.w);
  h1[0] = (short)f2bf(a.v2.x); h1[1] = (short)f2bf(a.v2.y);
  h1[2] = (short)f2bf(a.v2.z); h1[3] = (short)f2bf(a.v2.w);
  h1[4] = (short)f2bf(a.v3.x); h1[5] = (short)f2bf(a.v3.y);
  h1[6] = (short)f2bf(a.v3.z); h1[7] = (short)f2bf(a.v3.w);
  const int s = ar & 7;
  *(short8*)&L[ar * 64 + ((ag ^ s) * 8)] = h0;
  *(short8*)&L[ar * 64 + (((ag + 1) ^ s) * 8)] = h1;
}

// The R3-verified all-bf16 K-loop for k_bt256 (gate ledger unchanged):
//   ph0: stage A0(kt+1); vmcnt(6)|0; barrier; read af0+bf; q00; barrier
//   ph1: stage A1(kt+1); read af1; q01; barrier
//   ph2: stage B0(kt+2); q10; barrier
//   ph3: stage B1(kt+2); q11; barrier
#define KLOOP_256(Ap, ldA, Bp, ldB, NKT)                                       \
  for (int kt = 0; kt < (NKT); ++kt) {                                         \
    const unsigned short* Ah = As + ((kt & 1) * 2 + wm) * 8192;                \
    const unsigned short* Bh = Bs + ((kt & 1) * 2 + (wn >> 1)) * 8192;         \
    const int nbuf = 1 - (kt & 1);                                             \
    if (kt + 1 < (NKT)) {                                                      \
      stage_half((Ap) + (size_t)(kt + 1) * 64, (ldA),                          \
                 As + (nbuf * 2 + 0) * 8192, tid);                             \
      asm volatile("s_waitcnt vmcnt(6)" ::: "memory");                         \
    } else {                                                                   \
      asm volatile("s_waitcnt vmcnt(0)" ::: "memory");                         \
    }                                                                          \
    asm volatile("s_barrier" ::: "memory");                                    \
    _Pragma("unroll") for (int i = 0; i < 4; ++i)                              \
        _Pragma("unroll") for (int ks = 0; ks < 2; ++ks)                       \
            af[i][ks] = ldsfrag(Ah, i * 16 + lr, ks * 32 + lq * 8);            \
    _Pragma("unroll") for (int j = 0; j < 4; ++j)                              \
        _Pragma("unroll") for (int ks = 0; ks < 2; ++ks)                       \
            bf[j][ks] = ldsfrag(Bh, brow + j * 16 + lr, ks * 32 + lq * 8);     \
    __builtin_amdgcn_s_setprio(1);                                             \
    _Pragma("unroll") for (int i = 0; i < 4; ++i)                              \
        _Pragma("unroll") for (int j = 0; j < 2; ++j)                          \
            _Pragma("unroll") for (int ks = 0; ks < 2; ++ks)                   \
                acc[i][j] = __builtin_amdgcn_mfma_f32_16x16x32_bf16(           \
                    af[i][ks], bf[j][ks], acc[i][j], 0, 0, 0);                 \
    __builtin_amdgcn_s_setprio(0);                                             \
    asm volatile("s_barrier" ::: "memory");                                    \
    if (kt + 1 < (NKT))                                                        \
      stage_half((Ap) + 128 * (ldA) + (size_t)(kt + 1) * 64, (ldA),            \
                 As + (nbuf * 2 + 1) * 8192, tid);                             \
    _Pragma("unroll") for (int i = 0; i < 4; ++i)                              \
        _Pragma("unroll") for (int ks = 0; ks < 2; ++ks)                       \
            af1[i][ks] = ldsfrag(Ah, 64 + i * 16 + lr, ks * 32 + lq * 8);      \
    __builtin_amdgcn_s_setprio(1);                                             \
    _Pragma("unroll") for (int i = 0; i < 4; ++i)                              \
        _Pragma("unroll") for (int j = 0; j < 2; ++j)                          \
            _Pragma("unroll") for (int ks = 0; ks < 2; ++ks)                   \
                acc[i][2 + j] = __builtin_amdgcn_mfma_f32_16x16x32_bf16(       \
                    af[i][ks], bf[2 + j][ks], acc[i][2 + j], 0, 0, 0);         \
    __builtin_amdgcn_s_setprio(0);                                             \
    asm volatile("s_barrier" ::: "memory");                                    \
    if (kt + 2 < (NKT))                                                        \
      stage_half((Bp) + (size_t)(kt + 2) * 64, (ldB),                          \
                 Bs + ((kt & 1) * 2 + 0) * 8192, tid);                         \
    __builtin_amdgcn_s_setprio(1);                                             \
    _Pragma("unroll") for (int i = 0; i < 4; ++i)                              \
        _Pragma("unroll") for (int j = 0; j < 2; ++j)                          \
            _Pragma("unroll") for (int ks = 0; ks < 2; ++ks)                   \
                acc[4 + i][j] = __builtin_amdgcn_mfma_f32_16x16x32_bf16(       \
                    af1[i][ks], bf[j][ks], acc[4 + i][j], 0, 0, 0);            \
    __builtin_amdgcn_s_setprio(0);                                             \
    asm volatile("s_barrier" ::: "memory");                                    \
    if (kt + 2 < (NKT))                                                        \
      stage_half((Bp) + 128 * (ldB) + (size_t)(kt + 2) * 64, (ldB),            \
                 Bs + ((kt & 1) * 2 + 1) * 8192, tid);                         \
    __builtin_amdgcn_s_setprio(1);                                             \
    _Pragma("unroll") for (int i = 0; i < 4; ++i)                              \
        _Pragma("unroll") for (int j = 0; j < 2; ++j)                          \
            _Pragma("unroll") for (int ks = 0; ks < 2; ++ks)                   \
                acc[4 + i][2 + j] = __builtin_amdgcn_mfma_f32_16x16x32_bf16(   \
                    af1[i][ks], bf[2 + j][ks], acc[4 + i][2 + j], 0, 0, 0);    \
    __builtin_amdgcn_s_setprio(0);                                             \
    asm volatile("s_barrier" ::: "memory");                                    \
  }

#define PROLOGUE_256(Ap, ldA, Bp, ldB)                                         \
  stage_half((Bp), (ldB), Bs + 0 * 8192, tid);                                 \
  stage_half((Bp) + 128 * (ldB), (ldB), Bs + 1 * 8192, tid);                   \
  stage_half((Ap), (ldA), As + 0 * 8192, tid);                                 \
  stage_half((Ap) + 128 * (ldA), (ldA), As + 1 * 8192, tid);                   \
  stage_half((Bp) + 64, (ldB), Bs + 2 * 8192, tid);                            \
  stage_half((Bp) + 128 * (ldB) + 64, (ldB), Bs + 3 * 8192, tid);

// ---------------------------------------------------------------------------
// Fused projection GEMM, fp32 A read directly (conversion fused into staging).
//   grid.x = 6*mtiles (1-D, XCD-swizzled): nt 0 -> theta, 1 -> phi,
//   2..5 -> featsT columns (nt-2)*256.
// Per kt (R3 phase skeleton; B via gl_lds, A via reg-stage+convert):
//   ph0: issue A0(kt+1) fp32 loads; gate vmcnt(8)|0; barrier; read af0+bf;
//        q00; barrier
//   ph1: issue A1(kt+1) fp32 loads; q01; read af1; barrier
//   ph2: a_write A0(kt+1) (reg-dep drains its loads); stage B0(kt+2); q10;
//        barrier
//   ph3: a_write A1(kt+1); stage B1(kt+2); q11; lgkmcnt(0); barrier
// Gate ledger (per-wave issue order): at ph0 gate after issuing A0(kt+1):
//   outstanding = B0(kt+1)2 + B1(kt+1)2 [from ph2/3(kt-1) or prologue]
//                 + A0(kt+1)4  = 8  -> vmcnt(8) completes B(kt)+older. Uniform
//   for every kt with kt+1<NKT (checked kt=0, NKT-2); vmcnt(0) at kt=NKT-1.
// A-load drains are compiler-managed register deps (in-order vmcnt => a_write
// of the youngest A granule implies all older loads complete).
// WAR: A slot written at ph2/3(kt) was last read at ph0/1(kt-1): >=4 barriers.
// Visibility: lgkmcnt(0) before ph3 barrier; first read 2 barriers later.
// ---------------------------------------------------------------------------
__global__ __launch_bounds__(512, 2) void k_proj4(
    const float* __restrict__ batchF,            // [65536][1024] fp32
    const unsigned short* __restrict__ aT,
    const unsigned short* __restrict__ bT,
    const unsigned short* __restrict__ gT,
    const float* __restrict__ a_b, const float* __restrict__ b_b,
    const float* __restrict__ g_b,
    unsigned short* __restrict__ theta,
    unsigned short* __restrict__ phi,
    unsigned short* __restrict__ featsT) {
  __shared__ unsigned short lds[65536];  // 128 KiB
  unsigned short* As = lds;              // [(buf*2+half)*8192]
  unsigned short* Bs = lds + 32768;

  // T1: bijective XCD-chunked swizzle (gridDim.x % 8 == 0); the 6 same-mtile
  // blocks are consecutive logicals -> same XCD chunk -> A-panel L2 reuse.
  const int nwg = gridDim.x;
  const int hb = blockIdx.x;
  const int logical = (hb & 7) * (nwg >> 3) + (hb >> 3);
  const int nt = logical % 6;
  const int mtile = logical / 6;
  const int m0 = mtile * 256;

  const unsigned short* Wt; const float* bias; int nb0, mode;
  if (nt == 0)      { Wt = aT; bias = a_b; nb0 = 0;              mode = 0; }
  else if (nt == 1) { Wt = bT; bias = b_b; nb0 = 0;              mode = 1; }
  else              { Wt = gT; bias = g_b; nb0 = (nt - 2) * 256; mode = 2; }

  const int tid = threadIdx.x;
  const int wave = tid >> 6, lane = tid & 63;
  const int wm = wave >> 2, wn = wave & 3;
  const int lr = lane & 15, lq = lane >> 4;
  const int brow = (wn & 1) * 64;  // wave's local row base within its B half
  const int ar = tid >> 2;         // A-staging row 0..127
  const int ag = (tid & 3) * 2;    // A-staging first granule (of 8 floats)

  const float* Apf = batchF + (size_t)m0 * FF;       // [256][1024] fp32
  const unsigned short* Bp = Wt + (size_t)nb0 * FF;  // [256][1024] bf16

  floatx4 acc[8][4];
#pragma unroll
  for (int i = 0; i < 8; i++)
#pragma unroll
    for (int j = 0; j < 4; j++) acc[i][j] = (floatx4)0.0f;

  short8 af[4][2], af1[4][2], bf[4][2];
  A4 a0s, a1s;
  const int NKT = FF / 64;  // 16

  // Prologue. Issue order: B0(0) B1(0) | A0(0) A1(0) regs | B0(1) B1(1).
  // a_write(a0s) reg-dep waits vmcnt(8) -> drains B(0)+A0(0); B(1) in flight.
  stage_half(Bp,                 FF, Bs + 0 * 8192, tid);
  stage_half(Bp + 128 * FF,      FF, Bs + 1 * 8192, tid);
  a0s = a_load(Apf,            ar, ag);
  a1s = a_load(Apf + 128 * FF, ar, ag);
  stage_half(Bp + 64,            FF, Bs + 2 * 8192, tid);
  stage_half(Bp + 128 * FF + 64, FF, Bs + 3 * 8192, tid);
  a_write(As + 0 * 8192, ar, ag, a0s);
  a_write(As + 1 * 8192, ar, ag, a1s);
  asm volatile("s_waitcnt lgkmcnt(0)" ::: "memory");
  asm volatile("s_barrier" ::: "memory");

#pragma unroll 1
  for (int kt = 0; kt < NKT; ++kt) {
    const unsigned short* Ah = As + ((kt & 1) * 2 + wm) * 8192;
    const unsigned short* Bh = Bs + ((kt & 1) * 2 + (wn >> 1)) * 8192;
    const int nbuf = 1 - (kt & 1);

    // ---- phase 0: issue A0(kt+1); gate; barrier; read af0+bf; q00 ----
    if (kt + 1 < NKT) {
      a0s = a_load(Apf + (size_t)(kt + 1) * 64, ar, ag);
      asm volatile("s_waitcnt vmcnt(8)" ::: "memory");
    } else {
      asm volatile("s_waitcnt vmcnt(0)" ::: "memory");
    }
    asm volatile("s_barrier" ::: "memory");
#pragma unroll
    for (int i = 0; i < 4; ++i)
#pragma unroll
      for (int ks = 0; ks < 2; ++ks)
        af[i][ks] = ldsfrag(Ah, i * 16 + lr, ks * 32 + lq * 8);
#pragma unroll
    for (int j = 0; j < 4; ++j)
#pragma unroll
      for (int ks = 0; ks < 2; ++ks)
        bf[j][ks] = ldsfrag(Bh, brow + j * 16 + lr, ks * 32 + lq * 8);
    __builtin_amdgcn_s_setprio(1);
#pragma unroll
    for (int i = 0; i < 4; ++i)
#pragma unroll
      for (int j = 0; j < 2; ++j)
#pragma unroll
        for (int ks = 0; ks < 2; ++ks)
          acc[i][j] = __builtin_amdgcn_mfma_f32_16x16x32_bf16(
              af[i][ks], bf[j][ks], acc[i][j], 0, 0, 0);
    __builtin_amdgcn_s_setprio(0);
    asm volatile("s_barrier" ::: "memory");

    // ---- phase 1: issue A1(kt+1); q01; read af1 ----
    if (kt + 1 < NKT)
      a1s = a_load(Apf + 128 * FF + (size_t)(kt + 1) * 64, ar, ag);
    __builtin_amdgcn_s_setprio(1);
#pragma unroll
    for (int i = 0; i < 4; ++i)
#pragma unroll
      for (int j = 0; j < 2; ++j)
#pragma unroll
        for (int ks = 0; ks < 2; ++ks)
          acc[i][2 + j] = __builtin_amdgcn_mfma_f32_16x16x32_bf16(
              af[i][ks], bf[2 + j][ks], acc[i][2 + j], 0, 0, 0);
    __builtin_amdgcn_s_setprio(0);
#pragma unroll
    for (int i = 0; i < 4; ++i)
#pragma unroll
      for (int ks = 0; ks < 2; ++ks)
        af1[i][ks] = ldsfrag(Ah, 64 + i * 16 + lr, ks * 32 + lq * 8);
    asm volatile("s_barrier" ::: "memory");

    // ---- phase 2: write A0(kt+1); stage B0(kt+2); q10 ----
    if (kt + 1 < NKT) a_write(As + (nbuf * 2 + 0) * 8192, ar, ag, a0s);
    if (kt + 2 < NKT)
      stage_half(Bp + (size_t)(kt + 2) * 64, FF,
                 Bs + ((kt & 1) * 2 + 0) * 8192, tid);
    __builtin_amdgcn_s_setprio(1);
#pragma unroll
    for (int i = 0; i < 4; ++i)
#pragma unroll
      for (int j = 0; j < 2; ++j)
#pragma unroll
        for (int ks = 0; ks < 2; ++ks)
          acc[4 + i][j] = __builtin_amdgcn_mfma_f32_16x16x32_bf16(
              af1[i][ks], bf[j][ks], acc[4 + i][j], 0, 0, 0);
    __builtin_amdgcn_s_setprio(0);
    asm volatile("s_barrier" ::: "memory");

    // ---- phase 3: write A1(kt+1); stage B1(kt+2); q11; publish ----
    if (kt + 1 < NKT) a_write(As + (nbuf * 2 + 1) * 8192, ar, ag, a1s);
    if (kt + 2 < NKT)
      stage_half(Bp + 128 * FF + (size_t)(kt + 2) * 64, FF,
                 Bs + ((kt & 1) * 2 + 1) * 8192, tid);
    __builtin_amdgcn_s_setprio(1);
#pragma unroll
    for (int i = 0; i < 4; ++i)
#pragma unroll
      for (int j = 0; j < 2; ++j)
#pragma unroll
        for (int ks = 0; ks < 2; ++ks)
          acc[4 + i][2 + j] = __builtin_amdgcn_mfma_f32_16x16x32_bf16(
              af1[i][ks], bf[2 + j][ks], acc[4 + i][2 + j], 0, 0, 0);
    __builtin_amdgcn_s_setprio(0);
    asm volatile("s_waitcnt lgkmcnt(0)" ::: "memory");
    asm volatile("s_barrier" ::: "memory");
  }

  // Epilogue. C/D layout: col = lane&15, row = (lane>>4)*4 + reg.
#pragma unroll
  for (int fi = 0; fi < 8; ++fi) {
    const int srow = wm * 128 + fi * 16 + lq * 4;
#pragma unroll
    for (int j = 0; j < 4; ++j) {
      const int col = wn * 64 + j * 16 + lr;
      const float bv = bias[nb0 + col];
      if (mode == 2) {
        // featsT[t][f][s]; one t per 256-row tile; 4 s contiguous -> 8B store
        const int t = m0 >> 8;
        ushort4 h;
        h.x = f2bf(acc[fi][j][0] + bv);
        h.y = f2bf(acc[fi][j][1] + bv);
        h.z = f2bf(acc[fi][j][2] + bv);
        h.w = f2bf(acc[fi][j][3] + bv);
        *(ushort4*)&featsT[((size_t)t * FF + nb0 + col) * SS + srow] = h;
      } else {
        unsigned short* outp = (mode == 0) ? theta : phi;
#pragma unroll
        for (int rr = 0; rr < 4; ++rr)
          outp[(size_t)(m0 + srow + rr) * AA + col] = f2bf(acc[fi][j][rr] + bv);
      }
    }
  }
}

// ---------------------------------------------------------------------------
// Generic batched 256x256-tile bt-GEMM on the 8-phase structure (all bf16).
//   C[bz][m][n] = scale * sum_k A[bz][m][k] * B[bz][n][k],  M = 256 (one tile)
//   grid.x = batch * ntiles (XCD-chunk-swizzled when %8==0)
// ---------------------------------------------------------------------------
template <bool OUTF32>
__global__ __launch_bounds__(512, 2) void k_bt256(
    const unsigned short* __restrict__ A, const unsigned short* __restrict__ B,
    void* __restrict__ C, int ldA, int ldB, int K,
    long sA, long sB, long sC, int ntiles, float scale) {
  __shared__ unsigned short lds[65536];  // 128 KiB
  unsigned short* As = lds;
  unsigned short* Bs = lds + 32768;

  const int nwg = gridDim.x;
  const int hb = blockIdx.x;
  const int logical = (nwg & 7) ? hb : (hb & 7) * (nwg >> 3) + (hb >> 3);
  const int bz = logical / ntiles;
  const int n0 = (logical % ntiles) * 256;

  const int tid = threadIdx.x;
  const int wave = tid >> 6, lane = tid & 63;
  const int wm = wave >> 2, wn = wave & 3;
  const int lr = lane & 15, lq = lane >> 4;
  const int brow = (wn & 1) * 64;

  const unsigned short* Ap = A + (size_t)bz * sA;                      // [256][ldA]
  const unsigned short* Bp = B + (size_t)bz * sB + (size_t)n0 * ldB;   // [256][ldB]

  floatx4 acc[8][4];
#pragma unroll
  for (int i = 0; i < 8; i++)
#pragma unroll
    for (int j = 0; j < 4; j++) acc[i][j] = (floatx4)0.0f;

  short8 af[4][2], af1[4][2], bf[4][2];
  const int NKT = K / 64;

  PROLOGUE_256(Ap, ldA, Bp, ldB)
#pragma unroll 1
  KLOOP_256(Ap, ldA, Bp, ldB, NKT)

  const int ldC = ntiles * 256;
#pragma unroll
  for (int fi = 0; fi < 8; ++fi) {
    const int srow = wm * 128 + fi * 16 + lq * 4;
#pragma unroll
    for (int j = 0; j < 4; ++j) {
      const int col = n0 + wn * 64 + j * 16 + lr;
#pragma unroll
      for (int rr = 0; rr < 4; ++rr) {
        const float v = acc[fi][j][rr] * scale;
        if (OUTF32) {
          float* Cb = (float*)C + (size_t)bz * sC;
          Cb[(size_t)(srow + rr) * ldC + col] = v;
        } else {
          unsigned short* Cb = (unsigned short*)C + (size_t)bz * sC;
          Cb[(size_t)(srow + rr) * ldC + col] = f2bf(v);
        }
      }
    }
  }
}

// ---------------------------------------------------------------------------
extern "C" void kernel_launch(void* const* d_in, const int* in_sizes, int n_in,
                              void* d_out, int out_size, void* d_ws,
                              size_t ws_size, hipStream_t stream) {
  const float* batch = (const float*)d_in[0];
  const float* a_w   = (const float*)d_in[1];
  const float* a_b   = (const float*)d_in[2];
  const float* b_w   = (const float*)d_in[3];
  const float* b_b   = (const float*)d_in[4];
  const float* g_w   = (const float*)d_in[5];
  const float* g_b   = (const float*)d_in[6];
  float* out = (float*)d_out;

  // Workspace layout (bf16 elements). Total = 238,026,752 B (~227 MB).
  unsigned short* ws     = (unsigned short*)d_ws;
  unsigned short* aT     = ws;                                   // 256x1024
  unsigned short* bT     = aT + (size_t)AA * FF;                 // 256x1024
  unsigned short* gT     = bT + (size_t)AA * FF;                 // 1024x1024
  unsigned short* theta  = gT + (size_t)FF * FF;                 // 65536x256
  unsigned short* phi    = theta + (size_t)TT * SS * AA;         // 65536x256
  unsigned short* featsT = phi + (size_t)TT * SS * AA;           // [t][f][s]
  unsigned short* attn   = featsT + (size_t)TT * FF * SS;        // [t][s][r]

  dim3 tb(32, 8);
  k_transpose_cvt<<<dim3(32, 8),  tb, 0, stream>>>(a_w, aT, FF, AA);
  k_transpose_cvt<<<dim3(32, 8),  tb, 0, stream>>>(b_w, bT, FF, AA);
  k_transpose_cvt<<<dim3(32, 32), tb, 0, stream>>>(g_w, gT, FF, FF);

  // Fused projections straight from fp32 batch (conversion fused into
  // A-staging; no k_cvt pass, no batchH workspace).
  k_proj4<<<6 * 256, 512, 0, stream>>>(batch, aT, bT, gT, a_b, b_b, g_b,
                                       theta, phi, featsT);

  // attn[t] = theta[t] @ phi[t]^T   (M=N=K=256, batched over t)
  k_bt256<false><<<TT, 512, 0, stream>>>(
      theta, phi, attn, AA, AA, AA,
      (long)SS * AA, (long)SS * AA, (long)SS * SS, 1, 1.0f);

  // out[t] = (attn[t] @ featsT[t]^T) / 512   (M=256, N=1024, K=256)
  k_bt256<true><<<4 * TT, 512, 0, stream>>>(
      attn, featsT, out, SS, SS, SS,
      (long)SS * SS, (long)FF * SS, (long)SS * FF, 4, 1.0f / 512.0f);
}

// Round 8
// 421.182 us; speedup vs baseline: 1.1050x; 1.1050x over previous
//
#include <hip/hip_runtime.h>
#include <stdint.h>

// Problem dims (fixed by the reference)
#define TT 256
#define SS 256
#define FF 1024
#define AA 256

typedef __attribute__((ext_vector_type(8))) short short8;
typedef __attribute__((ext_vector_type(4))) float floatx4;

// fp32 -> bf16 round-to-nearest-even
__device__ __forceinline__ unsigned short f2bf(float f) {
  unsigned int u = __float_as_uint(f);
  u += 0x7FFFu + ((u >> 16) & 1u);
  return (unsigned short)(u >> 16);
}

// async global->LDS, 16 B per lane; LDS dest = wave-uniform base + lane*16
__device__ __forceinline__ void gl_lds16(const unsigned short* g, unsigned short* l) {
  __builtin_amdgcn_global_load_lds(
      (__attribute__((address_space(1))) void*)(g),
      (__attribute__((address_space(3))) void*)(l), 16, 0, 0);
}

// ---------------------------------------------------------------------------
// Weight transpose + fp32->bf16:  WT[n][k] = bf16(W[k][n]).  W: K x N fp32.
// (kept for the fallback path)
// ---------------------------------------------------------------------------
__global__ void k_transpose_cvt(const float* __restrict__ W,
                                unsigned short* __restrict__ WT,
                                int K, int N) {
  __shared__ float tile[32][33];
  const int bk = blockIdx.x * 32, bn = blockIdx.y * 32;
  const int tx = threadIdx.x, ty = threadIdx.y;
  for (int i = ty; i < 32; i += 8)
    tile[i][tx] = W[(size_t)(bk + i) * N + bn + tx];
  __syncthreads();
  for (int i = ty; i < 32; i += 8)
    WT[(size_t)(bn + i) * K + bk + tx] = f2bf(tile[tx][i]);
}

// ---------------------------------------------------------------------------
// Bulk fp32 -> bf16 convert (memory-bound, 8 elems/thread/iter).
// (kept for the fallback path)
// ---------------------------------------------------------------------------
__global__ __launch_bounds__(256) void k_cvt(const float* __restrict__ in,
                                             unsigned short* __restrict__ out,
                                             unsigned int n8) {
  unsigned int i = blockIdx.x * 256u + threadIdx.x;
  const unsigned int stride = gridDim.x * 256u;
  for (; i < n8; i += stride) {
    const size_t base = (size_t)i * 8;
    const floatx4 v0 = *(const floatx4*)(in + base);
    const floatx4 v1 = *(const floatx4*)(in + base + 4);
    ushort4 h0, h1;
    h0.x = f2bf(v0.x); h0.y = f2bf(v0.y); h0.z = f2bf(v0.z); h0.w = f2bf(v0.w);
    h1.x = f2bf(v1.x); h1.y = f2bf(v1.y); h1.z = f2bf(v1.z); h1.w = f2bf(v1.w);
    *(ushort4*)(out + base) = h0;
    *(ushort4*)(out + base + 4) = h1;
  }
}

// ---------------------------------------------------------------------------
// Fused prep: one dispatch does the full-batch fp32->bf16 convert AND the
// three weight transposes (the ~12 MB transpose traffic rides inside the
// memory-bound cvt dispatch; saves 3 launch gaps).
//   blocks [0, 2048):         grid-stride cvt of batch (65536x1024)
//   blocks [2048, 2304):      aT transpose  (32 x 8 tiles)
//   blocks [2304, 2560):      bT transpose  (32 x 8 tiles)
//   blocks [2560, 3584):      gT transpose  (32 x 32 tiles)
// ---------------------------------------------------------------------------
__global__ __launch_bounds__(256) void k_prep(
    const float* __restrict__ batch, unsigned short* __restrict__ batchH,
    const float* __restrict__ a_w, unsigned short* __restrict__ aT,
    const float* __restrict__ b_w, unsigned short* __restrict__ bT,
    const float* __restrict__ g_w, unsigned short* __restrict__ gT) {
  const int bid = blockIdx.x;
  if (bid < 2048) {
    const unsigned int n8 = (unsigned int)((size_t)TT * SS * FF / 8);
    unsigned int i = bid * 256u + threadIdx.x;
    for (; i < n8; i += 2048u * 256u) {
      const size_t base = (size_t)i * 8;
      const floatx4 v0 = *(const floatx4*)(batch + base);
      const floatx4 v1 = *(const floatx4*)(batch + base + 4);
      ushort4 h0, h1;
      h0.x = f2bf(v0.x); h0.y = f2bf(v0.y); h0.z = f2bf(v0.z); h0.w = f2bf(v0.w);
      h1.x = f2bf(v1.x); h1.y = f2bf(v1.y); h1.z = f2bf(v1.z); h1.w = f2bf(v1.w);
      *(ushort4*)(batchH + base) = h0;
      *(ushort4*)(batchH + base + 4) = h1;
    }
  } else {
    const int t = bid - 2048;
    const float* W; unsigned short* WT; int N, bx, by;
    if (t < 256)      { W = a_w; WT = aT; N = AA; bx = t % 32;        by = t / 32; }
    else if (t < 512) { W = b_w; WT = bT; N = AA; bx = (t - 256) % 32; by = (t - 256) / 32; }
    else              { W = g_w; WT = gT; N = FF; bx = (t - 512) % 32; by = (t - 512) / 32; }
    const int K = FF;
    __shared__ float tile[32][33];
    const int bk = bx * 32, bn = by * 32;
    const int tx = threadIdx.x & 31, ty = threadIdx.x >> 5;
    for (int i = ty; i < 32; i += 8)
      tile[i][tx] = W[(size_t)(bk + i) * N + bn + tx];
    __syncthreads();
    for (int i = ty; i < 32; i += 8)
      WT[(size_t)(bn + i) * K + bk + tx] = f2bf(tile[tx][i]);
  }
}

// ---------------------------------------------------------------------------
// Shared pieces for the 256x256 / BK=64 / 8-wave 8-phase GEMM structure.
// LDS 128 KiB: A[2buf][2half][128][64] | B[...]; half-tiles staged via
// global_load_lds with counted vmcnt (never 0 mid-loop).
// T2 swizzle: LDS granule gl of row r holds global granule gl ^ (r&7)
// (pre-swizzled source, rule #21); reads use col ^ ((row&7)<<3)
// -> conflict-free (measured 0).
// ---------------------------------------------------------------------------
__device__ __forceinline__ void stage_half(const unsigned short* G, int ld,
                                           unsigned short* L, int tid) {
  // G points at (row0, k0) of a 128x64 half-tile, leading dim = ld elems.
  const int wave = tid >> 6, lane = tid & 63;
#pragma unroll
  for (int c = 0; c < 2; ++c) {
    const int chunk = c * 8 + wave;            // 16 chunks of 8 rows
    const int r = chunk * 8 + (lane >> 3);     // local row 0..127
    const int k8 = (lane & 7) ^ (lane >> 3);   // swizzled source 16B-granule
    gl_lds16(G + (size_t)r * ld + k8 * 8, L + chunk * 512);
  }
}

__device__ __forceinline__ short8 ldsfrag(const unsigned short* h, int row,
                                          int col) {
  return *(const short8*)&h[row * 64 + (col ^ ((row & 7) << 3))];
}

// The R3-verified K-loop (8 barriers / K-tile, gate ledger):
//   ph0: stage A0(kt+1); vmcnt(6) [else 0]; barrier; read af0+bf; q00; barrier
//        (outstanding after issuing A0(kt+1) = B0,B1(kt+1)+A0(kt+1) = 6, so
//         vmcnt(6) completes ALL of tile kt incl. both A halves - all waves)
//   ph1: stage A1(kt+1); read af1; q01; barrier
//   ph2: stage B0(kt+2); q10; barrier
//   ph3: stage B1(kt+2); q11; barrier
#define KLOOP_256(Ap, ldA, Bp, ldB, NKT)                                       \
  for (int kt = 0; kt < (NKT); ++kt) {                                         \
    const unsigned short* Ah = As + ((kt & 1) * 2 + wm) * 8192;                \
    const unsigned short* Bh = Bs + ((kt & 1) * 2 + (wn >> 1)) * 8192;         \
    const int nbuf = 1 - (kt & 1);                                             \
    if (kt + 1 < (NKT)) {                                                      \
      stage_half((Ap) + (size_t)(kt + 1) * 64, (ldA),                          \
                 As + (nbuf * 2 + 0) * 8192, tid);                             \
      asm volatile("s_waitcnt vmcnt(6)" ::: "memory");                         \
    } else {                                                                   \
      asm volatile("s_waitcnt vmcnt(0)" ::: "memory");                         \
    }                                                                          \
    asm volatile("s_barrier" ::: "memory");                                    \
    _Pragma("unroll") for (int i = 0; i < 4; ++i)                              \
        _Pragma("unroll") for (int ks = 0; ks < 2; ++ks)                       \
            af[i][ks] = ldsfrag(Ah, i * 16 + lr, ks * 32 + lq * 8);            \
    _Pragma("unroll") for (int j = 0; j < 4; ++j)                              \
        _Pragma("unroll") for (int ks = 0; ks < 2; ++ks)                       \
            bf[j][ks] = ldsfrag(Bh, brow + j * 16 + lr, ks * 32 + lq * 8);     \
    __builtin_amdgcn_s_setprio(1);                                             \
    _Pragma("unroll") for (int i = 0; i < 4; ++i)                              \
        _Pragma("unroll") for (int j = 0; j < 2; ++j)                          \
            _Pragma("unroll") for (int ks = 0; ks < 2; ++ks)                   \
                acc[i][j] = __builtin_amdgcn_mfma_f32_16x16x32_bf16(           \
                    af[i][ks], bf[j][ks], acc[i][j], 0, 0, 0);                 \
    __builtin_amdgcn_s_setprio(0);                                             \
    asm volatile("s_barrier" ::: "memory");                                    \
    if (kt + 1 < (NKT))                                                        \
      stage_half((Ap) + 128 * (ldA) + (size_t)(kt + 1) * 64, (ldA),            \
                 As + (nbuf * 2 + 1) * 8192, tid);                             \
    _Pragma("unroll") for (int i = 0; i < 4; ++i)                              \
        _Pragma("unroll") for (int ks = 0; ks < 2; ++ks)                       \
            af1[i][ks] = ldsfrag(Ah, 64 + i * 16 + lr, ks * 32 + lq * 8);      \
    __builtin_amdgcn_s_setprio(1);                                             \
    _Pragma("unroll") for (int i = 0; i < 4; ++i)                              \
        _Pragma("unroll") for (int j = 0; j < 2; ++j)                          \
            _Pragma("unroll") for (int ks = 0; ks < 2; ++ks)                   \
                acc[i][2 + j] = __builtin_amdgcn_mfma_f32_16x16x32_bf16(       \
                    af[i][ks], bf[2 + j][ks], acc[i][2 + j], 0, 0, 0);         \
    __builtin_amdgcn_s_setprio(0);                                             \
    asm volatile("s_barrier" ::: "memory");                                    \
    if (kt + 2 < (NKT))                                                        \
      stage_half((Bp) + (size_t)(kt + 2) * 64, (ldB),                          \
                 Bs + ((kt & 1) * 2 + 0) * 8192, tid);                         \
    __builtin_amdgcn_s_setprio(1);                                             \
    _Pragma("unroll") for (int i = 0; i < 4; ++i)                              \
        _Pragma("unroll") for (int j = 0; j < 2; ++j)                          \
            _Pragma("unroll") for (int ks = 0; ks < 2; ++ks)                   \
                acc[4 + i][j] = __builtin_amdgcn_mfma_f32_16x16x32_bf16(       \
                    af1[i][ks], bf[j][ks], acc[4 + i][j], 0, 0, 0);            \
    __builtin_amdgcn_s_setprio(0);                                             \
    asm volatile("s_barrier" ::: "memory");                                    \
    if (kt + 2 < (NKT))                                                        \
      stage_half((Bp) + 128 * (ldB) + (size_t)(kt + 2) * 64, (ldB),            \
                 Bs + ((kt & 1) * 2 + 1) * 8192, tid);                         \
    __builtin_amdgcn_s_setprio(1);                                             \
    _Pragma("unroll") for (int i = 0; i < 4; ++i)                              \
        _Pragma("unroll") for (int j = 0; j < 2; ++j)                          \
            _Pragma("unroll") for (int ks = 0; ks < 2; ++ks)                   \
                acc[4 + i][2 + j] = __builtin_amdgcn_mfma_f32_16x16x32_bf16(   \
                    af1[i][ks], bf[2 + j][ks], acc[4 + i][2 + j], 0, 0, 0);    \
    __builtin_amdgcn_s_setprio(0);                                             \
    asm volatile("s_barrier" ::: "memory");                                    \
  }

#define PROLOGUE_256(Ap, ldA, Bp, ldB)                                         \
  stage_half((Bp), (ldB), Bs + 0 * 8192, tid);                                 \
  stage_half((Bp) + 128 * (ldB), (ldB), Bs + 1 * 8192, tid);                   \
  stage_half((Ap), (ldA), As + 0 * 8192, tid);                                 \
  stage_half((Ap) + 128 * (ldA), (ldA), As + 1 * 8192, tid);                   \
  stage_half((Bp) + 64, (ldB), Bs + 2 * 8192, tid);                            \
  stage_half((Bp) + 128 * (ldB) + 64, (ldB), Bs + 3 * 8192, tid);

// ---------------------------------------------------------------------------
// Fused projection GEMM (R3 schedule, measured 228 us / MfmaUtil 39.7).
//   grid.x = 6*mtiles (1-D, XCD-swizzled): nt 0 -> theta, 1 -> phi,
//   2..5 -> featsT columns (nt-2)*256.
// ---------------------------------------------------------------------------
__global__ __launch_bounds__(512, 2) void k_proj3(
    const unsigned short* __restrict__ batchH,   // chunk base [mtiles*256][FF]
    const unsigned short* __restrict__ aT,
    const unsigned short* __restrict__ bT,
    const unsigned short* __restrict__ gT,
    const float* __restrict__ a_b, const float* __restrict__ b_b,
    const float* __restrict__ g_b,
    unsigned short* __restrict__ theta,
    unsigned short* __restrict__ phi,
    unsigned short* __restrict__ featsT,
    int mbase) {
  __shared__ unsigned short lds[65536];  // 128 KiB
  unsigned short* As = lds;              // [(buf*2+half)*8192]
  unsigned short* Bs = lds + 32768;

  // T1: bijective XCD-chunked swizzle (gridDim.x % 8 == 0)
  const int nwg = gridDim.x;
  const int hb = blockIdx.x;
  const int logical = (hb & 7) * (nwg >> 3) + (hb >> 3);
  const int nt = logical % 6;
  const int mtile = logical / 6;
  const int m0l = mtile * 256;   // chunk-local
  const int m0 = mbase + m0l;    // global (multiple of 256)

  const unsigned short* Wt; const float* bias; int nb0, mode;
  if (nt == 0)      { Wt = aT; bias = a_b; nb0 = 0;              mode = 0; }
  else if (nt == 1) { Wt = bT; bias = b_b; nb0 = 0;              mode = 1; }
  else              { Wt = gT; bias = g_b; nb0 = (nt - 2) * 256; mode = 2; }

  const int tid = threadIdx.x;
  const int wave = tid >> 6, lane = tid & 63;
  const int wm = wave >> 2, wn = wave & 3;
  const int lr = lane & 15, lq = lane >> 4;
  const int brow = (wn & 1) * 64;  // wave's local row base within its B half

  const unsigned short* Ap = batchH + (size_t)m0l * FF;  // [256][1024]
  const unsigned short* Bp = Wt + (size_t)nb0 * FF;      // [256][1024]

  floatx4 acc[8][4];
#pragma unroll
  for (int i = 0; i < 8; i++)
#pragma unroll
    for (int j = 0; j < 4; j++) acc[i][j] = (floatx4)0.0f;

  short8 af[4][2], af1[4][2], bf[4][2];

  PROLOGUE_256(Ap, FF, Bp, FF)
#pragma unroll 1
  KLOOP_256(Ap, FF, Bp, FF, FF / 64)

  // Epilogue. C/D layout: col = lane&15, row = (lane>>4)*4 + reg.
#pragma unroll
  for (int fi = 0; fi < 8; ++fi) {
    const int srow = wm * 128 + fi * 16 + lq * 4;
#pragma unroll
    for (int j = 0; j < 4; ++j) {
      const int col = wn * 64 + j * 16 + lr;
      const float bv = bias[nb0 + col];
      if (mode == 2) {
        // featsT[t][f][s]; one t per 256-row tile; 4 s contiguous -> 8B store
        const int t = m0 >> 8;
        ushort4 h;
        h.x = f2bf(acc[fi][j][0] + bv);
        h.y = f2bf(acc[fi][j][1] + bv);
        h.z = f2bf(acc[fi][j][2] + bv);
        h.w = f2bf(acc[fi][j][3] + bv);
        *(ushort4*)&featsT[((size_t)t * FF + nb0 + col) * SS + srow] = h;
      } else {
        unsigned short* outp = (mode == 0) ? theta : phi;
#pragma unroll
        for (int rr = 0; rr < 4; ++rr)
          outp[(size_t)(m0 + srow + rr) * AA + col] = f2bf(acc[fi][j][rr] + bv);
      }
    }
  }
}

// ---------------------------------------------------------------------------
// Generic batched 256x256-tile bt-GEMM on the same 8-phase structure.
//   C[bz][m][n] = scale * sum_k A[bz][m][k] * B[bz][n][k],  M = 256 (one tile)
//   A: [256][ldA] per batch; B rows n0..n0+255 of [..][ldB]; C ld = ntiles*256
//   grid.x = batch * ntiles (XCD-chunk-swizzled when %8==0)
// ---------------------------------------------------------------------------
template <bool OUTF32>
__global__ __launch_bounds__(512, 2) void k_bt256(
    const unsigned short* __restrict__ A, const unsigned short* __restrict__ B,
    void* __restrict__ C, int ldA, int ldB, int K,
    long sA, long sB, long sC, int ntiles, float scale) {
  __shared__ unsigned short lds[65536];  // 128 KiB
  unsigned short* As = lds;
  unsigned short* Bs = lds + 32768;

  const int nwg = gridDim.x;
  const int hb = blockIdx.x;
  const int logical = (nwg & 7) ? hb : (hb & 7) * (nwg >> 3) + (hb >> 3);
  const int bz = logical / ntiles;
  const int n0 = (logical % ntiles) * 256;

  const int tid = threadIdx.x;
  const int wave = tid >> 6, lane = tid & 63;
  const int wm = wave >> 2, wn = wave & 3;
  const int lr = lane & 15, lq = lane >> 4;
  const int brow = (wn & 1) * 64;

  const unsigned short* Ap = A + (size_t)bz * sA;                      // [256][ldA]
  const unsigned short* Bp = B + (size_t)bz * sB + (size_t)n0 * ldB;   // [256][ldB]

  floatx4 acc[8][4];
#pragma unroll
  for (int i = 0; i < 8; i++)
#pragma unroll
    for (int j = 0; j < 4; j++) acc[i][j] = (floatx4)0.0f;

  short8 af[4][2], af1[4][2], bf[4][2];
  const int NKT = K / 64;

  PROLOGUE_256(Ap, ldA, Bp, ldB)
#pragma unroll 1
  KLOOP_256(Ap, ldA, Bp, ldB, NKT)

  const int ldC = ntiles * 256;
#pragma unroll
  for (int fi = 0; fi < 8; ++fi) {
    const int srow = wm * 128 + fi * 16 + lq * 4;
#pragma unroll
    for (int j = 0; j < 4; ++j) {
      const int col = n0 + wn * 64 + j * 16 + lr;
#pragma unroll
      for (int rr = 0; rr < 4; ++rr) {
        const float v = acc[fi][j][rr] * scale;
        if (OUTF32) {
          float* Cb = (float*)C + (size_t)bz * sC;
          Cb[(size_t)(srow + rr) * ldC + col] = v;
        } else {
          unsigned short* Cb = (unsigned short*)C + (size_t)bz * sC;
          Cb[(size_t)(srow + rr) * ldC + col] = f2bf(v);
        }
      }
    }
  }
}

// ---------------------------------------------------------------------------
extern "C" void kernel_launch(void* const* d_in, const int* in_sizes, int n_in,
                              void* d_out, int out_size, void* d_ws,
                              size_t ws_size, hipStream_t stream) {
  const float* batch = (const float*)d_in[0];
  const float* a_w   = (const float*)d_in[1];
  const float* a_b   = (const float*)d_in[2];
  const float* b_w   = (const float*)d_in[3];
  const float* b_b   = (const float*)d_in[4];
  const float* g_w   = (const float*)d_in[5];
  const float* g_b   = (const float*)d_in[6];
  float* out = (float*)d_out;

  // Workspace layout (bf16 elements). Base region = 238,026,752 B.
  unsigned short* ws     = (unsigned short*)d_ws;
  unsigned short* aT     = ws;                                   // 256x1024
  unsigned short* bT     = aT + (size_t)AA * FF;                 // 256x1024
  unsigned short* gT     = bT + (size_t)AA * FF;                 // 1024x1024
  unsigned short* theta  = gT + (size_t)FF * FF;                 // 65536x256
  unsigned short* phi    = theta + (size_t)TT * SS * AA;         // 65536x256
  unsigned short* featsT = phi + (size_t)TT * SS * AA;           // [t][f][s]
  unsigned short* attn   = featsT + (size_t)TT * FF * SS;        // [t][s][r]

  const size_t base_bytes  = 238026752ull;
  const size_t batch_bytes = (size_t)TT * SS * FF * 2;  // 128 MB bf16
  if (ws_size >= base_bytes + batch_bytes) {
    // Full path: one fused prep dispatch (cvt + 3 transposes), then a single
    // 1536-block proj dispatch.
    unsigned short* batchH = attn + (size_t)TT * SS * SS;
    k_prep<<<3584, 256, 0, stream>>>(batch, batchH, a_w, aT, b_w, bT, g_w, gT);
    k_proj3<<<6 * 256, 512, 0, stream>>>(batchH, aT, bT, gT, a_b, b_b, g_b,
                                         theta, phi, featsT, 0);
  } else {
    // Fallback: separate transposes; 4 chunks of 16384 rows, batchH aliases
    // attn (32 MB).
    dim3 tb(32, 8);
    k_transpose_cvt<<<dim3(32, 8),  tb, 0, stream>>>(a_w, aT, FF, AA);
    k_transpose_cvt<<<dim3(32, 8),  tb, 0, stream>>>(b_w, bT, FF, AA);
    k_transpose_cvt<<<dim3(32, 32), tb, 0, stream>>>(g_w, gT, FF, FF);
    unsigned short* batchH = attn;
    const int CHUNK_ROWS = 16384;
    for (int c = 0; c < 4; c++) {
      const float* src = batch + (size_t)c * CHUNK_ROWS * FF;
      k_cvt<<<2048, 256, 0, stream>>>(
          src, batchH, (unsigned int)((size_t)CHUNK_ROWS * FF / 8));
      k_proj3<<<6 * 64, 512, 0, stream>>>(batchH, aT, bT, gT, a_b, b_b, g_b,
                                          theta, phi, featsT, c * CHUNK_ROWS);
    }
  }

  // attn[t] = theta[t] @ phi[t]^T   (M=N=K=256, batched over t)
  k_bt256<false><<<TT, 512, 0, stream>>>(
      theta, phi, attn, AA, AA, AA,
      (long)SS * AA, (long)SS * AA, (long)SS * SS, 1, 1.0f);

  // out[t] = (attn[t] @ featsT[t]^T) / 512   (M=256, N=1024, K=256)
  k_bt256<true><<<4 * TT, 512, 0, stream>>>(
      attn, featsT, out, SS, SS, SS,
      (long)SS * SS, (long)FF * SS, (long)SS * FF, 4, 1.0f / 512.0f);
}